// Round 8
// baseline (90.003 us; speedup 1.0000x reference)
//
#include <hip/hip_runtime.h>
#include <hip/hip_bf16.h>

#define N_NODES 131072
#define BATCH 128
#define H 256
#define SPLIT 16   // chunks per GAP; grid = 128 gaps * SPLIT = 2048 blocks

typedef _Float16 half8 __attribute__((ext_vector_type(8)));
typedef float floatx4 __attribute__((ext_vector_type(4)));

// ---------------------------------------------------------------------------
// Pack W1 (f32 row-major KxN, K=H, N=H) into fragment-ordered f16 for
// mfma_f32_16x16x32_f16 B-operand.
// Chunk g = (ct*8 + ks)*64 + lane holds 8 f16:
//   W1[ks*32 + (lane>>4)*8 + j][ct*16 + (lane&15)], j=0..7
// ---------------------------------------------------------------------------
__global__ __launch_bounds__(256) void w1_pack_kernel(
    const float* __restrict__ W1, _Float16* __restrict__ W1p)
{
    const int g = blockIdx.x * 256 + threadIdx.x;   // [0, 8192)
    const int ct = g >> 9;
    const int ks = (g >> 6) & 7;
    const int l  = g & 63;
    const int k0 = ks * 32 + (l >> 4) * 8;
    const int col = ct * 16 + (l & 15);
    half8 h;
    #pragma unroll
    for (int j = 0; j < 8; ++j) h[j] = (_Float16)W1[(k0 + j) * H + col];
    reinterpret_cast<half8*>(W1p)[g] = h;
}

// ---------------------------------------------------------------------------
// Stage 1: escore[n] = exp(tanh(X[n,:] @ W1 + b1) @ W2 + b2) via f16 MFMA.
// Register-pressure-tuned: interleaved staging (low live range), ks-loop at
// unroll 1 so only one step's bf/af fragments are live (prevents the
// compiler hoisting all 32 W1p loads = 128 VGPRs), __launch_bounds__(256,4)
// caps VGPR at 128 -> 4 blocks/CU; cross-block TLP hides per-step latency.
// Max-free softmax: |score| <= ||W2||_1+|b2| ~ 13 -> exp f32-safe.
// ---------------------------------------------------------------------------
__global__ __launch_bounds__(256, 4) void scores_mfma_kernel(
    const float* __restrict__ X, const _Float16* __restrict__ W1p,
    const float* __restrict__ b1, const float* __restrict__ W2,
    const float* __restrict__ b2, float* __restrict__ escore)
{
    __shared__ __align__(16) _Float16 Xs[64 * H];   // 32 KB, swizzled
    __shared__ float sp[4][64];

    const int tid = threadIdx.x;
    const int wave = tid >> 6;
    const int lane = tid & 63;
    const long long base = (long long)blockIdx.x * 64;

    // ---- stage X tile: 64 rows x 256 cols f32 -> f16 LDS (swizzled) ----
    {
        const float4* Xv = reinterpret_cast<const float4*>(X + base * H);
        #pragma unroll
        for (int i = 0; i < 8; ++i) {
            const int c = tid + i * 256;
            const int row = c >> 5;
            const int col8 = c & 31;
            float4 a  = Xv[row * 64 + col8 * 2];
            float4 bq = Xv[row * 64 + col8 * 2 + 1];
            half8 h;
            h[0] = (_Float16)a.x;  h[1] = (_Float16)a.y;
            h[2] = (_Float16)a.z;  h[3] = (_Float16)a.w;
            h[4] = (_Float16)bq.x; h[5] = (_Float16)bq.y;
            h[6] = (_Float16)bq.z; h[7] = (_Float16)bq.w;
            int byte = row * 512 + col8 * 16;
            byte ^= (row & 7) << 4;
            *reinterpret_cast<half8*>(reinterpret_cast<char*>(Xs) + byte) = h;
        }
    }
    __syncthreads();

    floatx4 acc[4][4];
    #pragma unroll
    for (int rt = 0; rt < 4; ++rt)
        #pragma unroll
        for (int ctl = 0; ctl < 4; ++ctl)
            acc[rt][ctl] = (floatx4){0.f, 0.f, 0.f, 0.f};

    // wave's B pointer: chunk index = wave*2048 + ctl*512 + ks*64 + lane
    const half8* Bw = reinterpret_cast<const half8*>(W1p) + wave * 2048 + lane;

    #pragma unroll 1
    for (int ks = 0; ks < 8; ++ks) {
        half8 bf0 = Bw[ks * 64];
        half8 bf1 = Bw[512 + ks * 64];
        half8 bf2 = Bw[1024 + ks * 64];
        half8 bf3 = Bw[1536 + ks * 64];
        half8 af[4];
        #pragma unroll
        for (int rt = 0; rt < 4; ++rt) {
            const int row = rt * 16 + (lane & 15);
            int byte = row * 512 + ks * 64 + (lane >> 4) * 16;
            byte ^= (row & 7) << 4;
            af[rt] = *reinterpret_cast<const half8*>(
                reinterpret_cast<const char*>(Xs) + byte);
        }
        #pragma unroll
        for (int rt = 0; rt < 4; ++rt) {
            acc[rt][0] = __builtin_amdgcn_mfma_f32_16x16x32_f16(af[rt], bf0, acc[rt][0], 0, 0, 0);
            acc[rt][1] = __builtin_amdgcn_mfma_f32_16x16x32_f16(af[rt], bf1, acc[rt][1], 0, 0, 0);
            acc[rt][2] = __builtin_amdgcn_mfma_f32_16x16x32_f16(af[rt], bf2, acc[rt][2], 0, 0, 0);
            acc[rt][3] = __builtin_amdgcn_mfma_f32_16x16x32_f16(af[rt], bf3, acc[rt][3], 0, 0, 0);
        }
    }

    // ---- epilogue: tanh + W2 dot + exp ----
    float w2v[4], b1v[4];
    #pragma unroll
    for (int ctl = 0; ctl < 4; ++ctl) {
        const int col = wave * 64 + ctl * 16 + (lane & 15);
        w2v[ctl] = W2[col];
        b1v[ctl] = b1[col];
    }

    float sc[4][4];
    #pragma unroll
    for (int rt = 0; rt < 4; ++rt) {
        #pragma unroll
        for (int reg = 0; reg < 4; ++reg) {
            float s = 0.f;
            #pragma unroll
            for (int ctl = 0; ctl < 4; ++ctl) {
                const float x = acc[rt][ctl][reg] + b1v[ctl];
                const float t = 1.f - 2.f / (__expf(2.f * x) + 1.f);
                s = fmaf(t, w2v[ctl], s);
            }
            sc[rt][reg] = s;
        }
    }
    #pragma unroll
    for (int off = 1; off < 16; off <<= 1)
        #pragma unroll
        for (int rt = 0; rt < 4; ++rt)
            #pragma unroll
            for (int reg = 0; reg < 4; ++reg)
                sc[rt][reg] += __shfl_xor(sc[rt][reg], off);

    if ((lane & 15) == 0) {
        #pragma unroll
        for (int rt = 0; rt < 4; ++rt)
            #pragma unroll
            for (int reg = 0; reg < 4; ++reg)
                sp[wave][rt * 16 + (lane >> 4) * 4 + reg] = sc[rt][reg];
    }
    __syncthreads();
    if (tid < 64)
        escore[base + tid] =
            __expf(sp[0][tid] + sp[1][tid] + sp[2][tid] + sp[3][tid] + b2[0]);
}

// ---------------------------------------------------------------------------
// Stage 2a: per-(gap, chunk) single-pass aggregation (max-free).
// gap g = [offsets[g], offsets[g+1]) (g=127 -> N). Wave w handles rows
// i == w (mod 4); p = escore[i] is a wave-uniform load; acc += p*x;
// z += p. No LDS broadcast, no in-loop syncs.
// ---------------------------------------------------------------------------
__global__ __launch_bounds__(256) void partial_kernel(
    const float* __restrict__ X, const float* __restrict__ escore,
    const int* __restrict__ offsets,
    float* __restrict__ pz, float* __restrict__ pacc)
{
    const int gp = blockIdx.x >> 4;      // gap id, 0..127
    const int s = blockIdx.x & 15;       // chunk within gap
    const int tid = threadIdx.x;
    const int lane = tid & 63;
    const int wave = tid >> 6;

    const int gs = offsets[gp];
    const int ge = (gp == BATCH - 1) ? N_NODES : offsets[gp + 1];
    const int L = ge - gs;
    const int chunk = (L + SPLIT - 1) / SPLIT;
    const int cs = gs + s * chunk;
    const int ce = min(cs + chunk, ge);

    const float4* X4 = reinterpret_cast<const float4*>(X);

    float4 acc = {0.f, 0.f, 0.f, 0.f};
    float z = 0.f;
    for (int i = cs + wave; i < ce; i += 4) {
        const float p = escore[i];
        float4 xv = X4[(long long)i * 64 + lane];
        acc.x = fmaf(p, xv.x, acc.x);
        acc.y = fmaf(p, xv.y, acc.y);
        acc.z = fmaf(p, xv.z, acc.z);
        acc.w = fmaf(p, xv.w, acc.w);
        z += p;
    }

    __shared__ float accL[4][H];
    __shared__ float zL[4];
    reinterpret_cast<float4*>(&accL[wave][0])[lane] = acc;
    if (lane == 0) zL[wave] = z;
    __syncthreads();
    pacc[(long long)blockIdx.x * H + tid] =
        accL[0][tid] + accL[1][tid] + accL[2][tid] + accL[3][tid];
    if (tid == 0) pz[blockIdx.x] = zL[0] + zL[1] + zL[2] + zL[3];
}

// ---------------------------------------------------------------------------
// Stage 2b: segment b = union of gaps [max(b-1,0), min(b+1,127)].
// Plain sums (max-free), out = r / z.
// ---------------------------------------------------------------------------
__global__ __launch_bounds__(256) void reduce_kernel(
    const float* __restrict__ pz, const float* __restrict__ pacc,
    float* __restrict__ out)
{
    const int b = blockIdx.x;
    const int tid = threadIdx.x;
    const int g0 = (b == 0) ? 0 : b - 1;
    const int g1 = (b >= BATCH - 1) ? BATCH - 1 : b + 1;
    const int s0 = g0 * SPLIT;
    const int s1 = (g1 + 1) * SPLIT;   // exclusive

    float z = 0.f, r = 0.f;
    for (int s = s0; s < s1; ++s) {
        z += pz[s];
        r += pacc[(long long)s * H + tid];
    }
    out[b * H + tid] = r / z;
}

// ---------------------------------------------------------------------------
extern "C" void kernel_launch(void* const* d_in, const int* in_sizes, int n_in,
                              void* d_out, int out_size, void* d_ws, size_t ws_size,
                              hipStream_t stream)
{
    const float* X     = (const float*)d_in[0];
    const int* offs    = (const int*)d_in[1];   // int64 in ref -> int32 on device
    const float* W1    = (const float*)d_in[2];
    const float* b1    = (const float*)d_in[3];
    const float* W2    = (const float*)d_in[4];
    const float* b2    = (const float*)d_in[5];
    float* out         = (float*)d_out;

    // workspace layout (floats):
    //   [0, N)               escore
    //   [N, N+BS)            pz      (BS = 2048)
    //   [N+BS, N+BS+BS*H)    pacc
    //   [.., +32768)         W1p (65536 f16)
    float* escore = (float*)d_ws;
    float* pz     = escore + N_NODES;
    float* pacc   = pz + BATCH * SPLIT;
    _Float16* W1p = (_Float16*)(pacc + (size_t)BATCH * SPLIT * H);

    w1_pack_kernel<<<32, 256, 0, stream>>>(W1, W1p);
    scores_mfma_kernel<<<N_NODES / 64, 256, 0, stream>>>(X, W1p, b1, W2, b2, escore);
    partial_kernel<<<BATCH * SPLIT, 256, 0, stream>>>(X, escore, offs, pz, pacc);
    reduce_kernel<<<BATCH, 256, 0, stream>>>(pz, pacc, out);
}

// Round 9
// 69.796 us; speedup vs baseline: 1.2895x; 1.2895x over previous
//
#include <hip/hip_runtime.h>
#include <hip/hip_bf16.h>

#define N_NODES 131072
#define BATCH 128
#define H 256
#define NTILES (N_NODES / 64)   // 2048 node tiles of 64 rows

typedef _Float16 half8 __attribute__((ext_vector_type(8)));
typedef float floatx4 __attribute__((ext_vector_type(4)));

// ---------------------------------------------------------------------------
// Prep: blocks 0..31 pack W1 into MFMA fragment order (f16); blocks 32..159
// zero pacc (128*256) ; block 32 also zeros pz (128). Runs every call so the
// atomic accumulators start from zero on each graph replay.
// ---------------------------------------------------------------------------
__global__ __launch_bounds__(256) void prep_kernel(
    const float* __restrict__ W1, _Float16* __restrict__ W1p,
    float* __restrict__ pacc, float* __restrict__ pz)
{
    const int bid = blockIdx.x;
    const int tid = threadIdx.x;
    if (bid < 32) {
        const int g = bid * 256 + tid;          // [0, 8192)
        const int ct = g >> 9;
        const int ks = (g >> 6) & 7;
        const int l  = g & 63;
        const int k0 = ks * 32 + (l >> 4) * 8;
        const int col = ct * 16 + (l & 15);
        half8 h;
        #pragma unroll
        for (int j = 0; j < 8; ++j) h[j] = (_Float16)W1[(k0 + j) * H + col];
        reinterpret_cast<half8*>(W1p)[g] = h;
    } else {
        pacc[(bid - 32) * 256 + tid] = 0.f;     // 128*256 = 32768 exactly
        if (bid == 32 && tid < BATCH) pz[tid] = 0.f;
    }
}

// ---------------------------------------------------------------------------
// FUSED single pass over node tiles. Tile t = rows [64t, 64t+64).
//   1. stage X tile f32->f16 into XOR-swizzled LDS (HBM: X read ONCE here)
//   2. f16 MFMA (unroll-1 ks loop, low VGPR) -> tanh -> W2 dot ->
//      p[row] = exp(score) in LDS  (max-free softmax: |score| <= ~13)
//   3. for each gap overlapping the tile (usually 1): acc += p*x with x
//      re-read f32 from L2-hot lines; per-gap atomicAdd into pacc/pz.
// Gap g = [off[g], off[g+1]) (g=127 -> N); rows < off[0] belong to no gap.
// Atomic f32 adds are order-independent math; rounding jitter ~1e-6.
// ---------------------------------------------------------------------------
__global__ __launch_bounds__(256, 4) void fused_kernel(
    const float* __restrict__ X, const _Float16* __restrict__ W1p,
    const float* __restrict__ b1, const float* __restrict__ W2,
    const float* __restrict__ b2, const int* __restrict__ offsets,
    float* __restrict__ pacc, float* __restrict__ pz)
{
    __shared__ __align__(16) _Float16 Xs[64 * H];   // 32 KB, swizzled
    __shared__ float sp[4][64];
    __shared__ float scL[64];
    __shared__ float accL[4][H];
    __shared__ float zLs[4];
    __shared__ int offL[BATCH];

    const int tid = threadIdx.x;
    const int wave = tid >> 6;
    const int lane = tid & 63;
    const int t0 = blockIdx.x * 64;

    if (tid < BATCH) offL[tid] = offsets[tid];

    // ---- 1. stage X tile ----
    {
        const float4* Xv = reinterpret_cast<const float4*>(X + (long long)t0 * H);
        #pragma unroll
        for (int i = 0; i < 8; ++i) {
            const int c = tid + i * 256;
            const int row = c >> 5;
            const int col8 = c & 31;
            float4 a  = Xv[row * 64 + col8 * 2];
            float4 bq = Xv[row * 64 + col8 * 2 + 1];
            half8 h;
            h[0] = (_Float16)a.x;  h[1] = (_Float16)a.y;
            h[2] = (_Float16)a.z;  h[3] = (_Float16)a.w;
            h[4] = (_Float16)bq.x; h[5] = (_Float16)bq.y;
            h[6] = (_Float16)bq.z; h[7] = (_Float16)bq.w;
            int byte = row * 512 + col8 * 16;
            byte ^= (row & 7) << 4;
            *reinterpret_cast<half8*>(reinterpret_cast<char*>(Xs) + byte) = h;
        }
    }
    __syncthreads();   // Xs + offL ready

    // ---- 2. MFMA scores ----
    floatx4 acc[4][4];
    #pragma unroll
    for (int rt = 0; rt < 4; ++rt)
        #pragma unroll
        for (int ctl = 0; ctl < 4; ++ctl)
            acc[rt][ctl] = (floatx4){0.f, 0.f, 0.f, 0.f};

    const half8* Bw = reinterpret_cast<const half8*>(W1p) + wave * 2048 + lane;

    #pragma unroll 1
    for (int ks = 0; ks < 8; ++ks) {
        half8 bf0 = Bw[ks * 64];
        half8 bf1 = Bw[512 + ks * 64];
        half8 bf2 = Bw[1024 + ks * 64];
        half8 bf3 = Bw[1536 + ks * 64];
        half8 af[4];
        #pragma unroll
        for (int rt = 0; rt < 4; ++rt) {
            const int row = rt * 16 + (lane & 15);
            int byte = row * 512 + ks * 64 + (lane >> 4) * 16;
            byte ^= (row & 7) << 4;
            af[rt] = *reinterpret_cast<const half8*>(
                reinterpret_cast<const char*>(Xs) + byte);
        }
        #pragma unroll
        for (int rt = 0; rt < 4; ++rt) {
            acc[rt][0] = __builtin_amdgcn_mfma_f32_16x16x32_f16(af[rt], bf0, acc[rt][0], 0, 0, 0);
            acc[rt][1] = __builtin_amdgcn_mfma_f32_16x16x32_f16(af[rt], bf1, acc[rt][1], 0, 0, 0);
            acc[rt][2] = __builtin_amdgcn_mfma_f32_16x16x32_f16(af[rt], bf2, acc[rt][2], 0, 0, 0);
            acc[rt][3] = __builtin_amdgcn_mfma_f32_16x16x32_f16(af[rt], bf3, acc[rt][3], 0, 0, 0);
        }
    }

    // epilogue: tanh + W2 dot -> per-row exp(score) in scL
    float w2v[4], b1v[4];
    #pragma unroll
    for (int ctl = 0; ctl < 4; ++ctl) {
        const int col = wave * 64 + ctl * 16 + (lane & 15);
        w2v[ctl] = W2[col];
        b1v[ctl] = b1[col];
    }

    float sc[4][4];
    #pragma unroll
    for (int rt = 0; rt < 4; ++rt) {
        #pragma unroll
        for (int reg = 0; reg < 4; ++reg) {
            float s = 0.f;
            #pragma unroll
            for (int ctl = 0; ctl < 4; ++ctl) {
                const float x = acc[rt][ctl][reg] + b1v[ctl];
                const float t = 1.f - 2.f / (__expf(2.f * x) + 1.f);
                s = fmaf(t, w2v[ctl], s);
            }
            sc[rt][reg] = s;
        }
    }
    #pragma unroll
    for (int off = 1; off < 16; off <<= 1)
        #pragma unroll
        for (int rt = 0; rt < 4; ++rt)
            #pragma unroll
            for (int reg = 0; reg < 4; ++reg)
                sc[rt][reg] += __shfl_xor(sc[rt][reg], off);

    if ((lane & 15) == 0) {
        #pragma unroll
        for (int rt = 0; rt < 4; ++rt)
            #pragma unroll
            for (int reg = 0; reg < 4; ++reg)
                sp[wave][rt * 16 + (lane >> 4) * 4 + reg] = sc[rt][reg];
    }
    __syncthreads();
    if (tid < 64)
        scL[tid] = __expf(sp[0][tid] + sp[1][tid] + sp[2][tid] + sp[3][tid] + b2[0]);
    __syncthreads();

    // ---- 3. per-gap aggregation with atomics ----
    // gap(node) = largest g with offL[g] <= node, or -1 if node < offL[0]
    int g_lo, g_hi;
    {
        int node = t0;
        if (node < offL[0]) g_lo = -1;
        else {
            int lo = 0, hi = BATCH - 1;
            while (lo < hi) { int mid = (lo + hi + 1) >> 1; if (offL[mid] <= node) lo = mid; else hi = mid - 1; }
            g_lo = lo;
        }
        node = t0 + 63;
        if (node < offL[0]) g_hi = -1;
        else {
            int lo = 0, hi = BATCH - 1;
            while (lo < hi) { int mid = (lo + hi + 1) >> 1; if (offL[mid] <= node) lo = mid; else hi = mid - 1; }
            g_hi = lo;
        }
    }

    const float4* X4 = reinterpret_cast<const float4*>(X);
    for (int g = (g_lo < 0 ? 0 : g_lo); g <= g_hi; ++g) {
        const int rs = max(t0, offL[g]);
        const int re = min(t0 + 64, (g == BATCH - 1) ? N_NODES : offL[g + 1]);

        float4 a4 = {0.f, 0.f, 0.f, 0.f};
        float z = 0.f;
        for (int i = rs + wave; i < re; i += 4) {
            const float p = scL[i - t0];
            float4 xv = X4[(long long)i * 64 + lane];
            a4.x = fmaf(p, xv.x, a4.x);
            a4.y = fmaf(p, xv.y, a4.y);
            a4.z = fmaf(p, xv.z, a4.z);
            a4.w = fmaf(p, xv.w, a4.w);
            z += p;
        }
        reinterpret_cast<float4*>(&accL[wave][0])[lane] = a4;
        if (lane == 0) zLs[wave] = z;
        __syncthreads();
        const float v = accL[0][tid] + accL[1][tid] + accL[2][tid] + accL[3][tid];
        atomicAdd(&pacc[g * H + tid], v);
        if (tid == 0) atomicAdd(&pz[g], zLs[0] + zLs[1] + zLs[2] + zLs[3]);
        __syncthreads();   // accL reused by next gap
    }
}

// ---------------------------------------------------------------------------
// Reduce: segment b = union of gaps [max(b-1,0), min(b+1,127)].
// out = sum(acc_g) / sum(z_g). 128 blocks x 256 threads.
// ---------------------------------------------------------------------------
__global__ __launch_bounds__(256) void reduce_kernel(
    const float* __restrict__ pacc, const float* __restrict__ pz,
    float* __restrict__ out)
{
    const int b = blockIdx.x;
    const int tid = threadIdx.x;
    const int g0 = (b == 0) ? 0 : b - 1;
    const int g1 = (b >= BATCH - 1) ? BATCH - 1 : b + 1;

    float r = 0.f, z = 0.f;
    for (int g = g0; g <= g1; ++g) {
        r += pacc[g * H + tid];
        z += pz[g];
    }
    out[b * H + tid] = r / z;
}

// ---------------------------------------------------------------------------
extern "C" void kernel_launch(void* const* d_in, const int* in_sizes, int n_in,
                              void* d_out, int out_size, void* d_ws, size_t ws_size,
                              hipStream_t stream)
{
    const float* X     = (const float*)d_in[0];
    const int* offs    = (const int*)d_in[1];   // int64 in ref -> int32 on device
    const float* W1    = (const float*)d_in[2];
    const float* b1    = (const float*)d_in[3];
    const float* W2    = (const float*)d_in[4];
    const float* b2    = (const float*)d_in[5];
    float* out         = (float*)d_out;

    // workspace layout (floats):
    //   [0, 32768)        pacc   (128 gaps x 256)
    //   [32768, 32896)    pz     (128)
    //   [32896, ...)      W1p    (65536 f16 = 128 KB)
    float* pacc   = (float*)d_ws;
    float* pz     = pacc + BATCH * H;
    _Float16* W1p = (_Float16*)(pz + BATCH);

    prep_kernel<<<160, 256, 0, stream>>>(W1, W1p, pacc, pz);
    fused_kernel<<<NTILES, 256, 0, stream>>>(X, W1p, b1, W2, b2, offs, pacc, pz);
    reduce_kernel<<<BATCH, 256, 0, stream>>>(pacc, pz, out);
}

// Round 10
// 61.238 us; speedup vs baseline: 1.4697x; 1.1397x over previous
//
#include <hip/hip_runtime.h>
#include <hip/hip_bf16.h>

#define N_NODES 131072
#define BATCH 128
#define H 256
#define NTILES (N_NODES / 64)   // 2048 node tiles of 64 rows

typedef _Float16 half8 __attribute__((ext_vector_type(8)));
typedef _Float16 half4 __attribute__((ext_vector_type(4)));
typedef float floatx4 __attribute__((ext_vector_type(4)));

// ---------------------------------------------------------------------------
// Prep: blocks 0..31 pack W1 into MFMA fragment order (f16); blocks 32..159
// zero pacc (128*256); block 32 also zeros pz (128). Runs every call so the
// atomic accumulators start from zero on each graph replay.
// ---------------------------------------------------------------------------
__global__ __launch_bounds__(256) void prep_kernel(
    const float* __restrict__ W1, _Float16* __restrict__ W1p,
    float* __restrict__ pacc, float* __restrict__ pz)
{
    const int bid = blockIdx.x;
    const int tid = threadIdx.x;
    if (bid < 32) {
        const int g = bid * 256 + tid;          // [0, 8192)
        const int ct = g >> 9;
        const int ks = (g >> 6) & 7;
        const int l  = g & 63;
        const int k0 = ks * 32 + (l >> 4) * 8;
        const int col = ct * 16 + (l & 15);
        half8 h;
        #pragma unroll
        for (int j = 0; j < 8; ++j) h[j] = (_Float16)W1[(k0 + j) * H + col];
        reinterpret_cast<half8*>(W1p)[g] = h;
    } else {
        pacc[(bid - 32) * 256 + tid] = 0.f;     // 128*256 = 32768 exactly
        if (bid == 32 && tid < BATCH) pz[tid] = 0.f;
    }
}

// ---------------------------------------------------------------------------
// FUSED single pass over node tiles. Tile t = rows [64t, 64t+64).
//   1. stage X tile f32->f16 into XOR-swizzled LDS (HBM: X read ONCE, here)
//   2. f16 MFMA (unroll-2 ks loop: next step's B-fragments pipeline above
//      current MFMAs) -> tanh -> W2 dot -> p[row]=exp(score) in LDS
//      (max-free softmax: |score| <= ||W2||_1+|b2| ~ 13, exp f32-safe)
//   3. per overlapping gap: acc += p * x  with x read from the f16 LDS tile
//      (NO global re-read; phase is pure LDS+VALU); atomicAdd into pacc/pz.
// Gap g = [off[g], off[g+1]) (g=127 -> N); rows < off[0] belong to no gap.
// ---------------------------------------------------------------------------
__global__ __launch_bounds__(256, 4) void fused_kernel(
    const float* __restrict__ X, const _Float16* __restrict__ W1p,
    const float* __restrict__ b1, const float* __restrict__ W2,
    const float* __restrict__ b2, const int* __restrict__ offsets,
    float* __restrict__ pacc, float* __restrict__ pz)
{
    __shared__ __align__(16) _Float16 Xs[64 * H];   // 32 KB, swizzled
    __shared__ float sp[4][64];
    __shared__ float scL[64];
    __shared__ float accL[4][H];
    __shared__ float zLs[4];
    __shared__ int offL[BATCH];

    const int tid = threadIdx.x;
    const int wave = tid >> 6;
    const int lane = tid & 63;
    const int t0 = blockIdx.x * 64;

    if (tid < BATCH) offL[tid] = offsets[tid];

    // ---- 1. stage X tile ----
    {
        const float4* Xv = reinterpret_cast<const float4*>(X + (long long)t0 * H);
        #pragma unroll
        for (int i = 0; i < 8; ++i) {
            const int c = tid + i * 256;
            const int row = c >> 5;
            const int col8 = c & 31;
            float4 a  = Xv[row * 64 + col8 * 2];
            float4 bq = Xv[row * 64 + col8 * 2 + 1];
            half8 h;
            h[0] = (_Float16)a.x;  h[1] = (_Float16)a.y;
            h[2] = (_Float16)a.z;  h[3] = (_Float16)a.w;
            h[4] = (_Float16)bq.x; h[5] = (_Float16)bq.y;
            h[6] = (_Float16)bq.z; h[7] = (_Float16)bq.w;
            int byte = row * 512 + col8 * 16;
            byte ^= (row & 7) << 4;
            *reinterpret_cast<half8*>(reinterpret_cast<char*>(Xs) + byte) = h;
        }
    }
    __syncthreads();   // Xs + offL ready

    // ---- 2. MFMA scores ----
    floatx4 acc[4][4];
    #pragma unroll
    for (int rt = 0; rt < 4; ++rt)
        #pragma unroll
        for (int ctl = 0; ctl < 4; ++ctl)
            acc[rt][ctl] = (floatx4){0.f, 0.f, 0.f, 0.f};

    const half8* Bw = reinterpret_cast<const half8*>(W1p) + wave * 2048 + lane;

    #pragma unroll 2
    for (int ks = 0; ks < 8; ++ks) {
        half8 bf0 = Bw[ks * 64];
        half8 bf1 = Bw[512 + ks * 64];
        half8 bf2 = Bw[1024 + ks * 64];
        half8 bf3 = Bw[1536 + ks * 64];
        half8 af[4];
        #pragma unroll
        for (int rt = 0; rt < 4; ++rt) {
            const int row = rt * 16 + (lane & 15);
            int byte = row * 512 + ks * 64 + (lane >> 4) * 16;
            byte ^= (row & 7) << 4;
            af[rt] = *reinterpret_cast<const half8*>(
                reinterpret_cast<const char*>(Xs) + byte);
        }
        #pragma unroll
        for (int rt = 0; rt < 4; ++rt) {
            acc[rt][0] = __builtin_amdgcn_mfma_f32_16x16x32_f16(af[rt], bf0, acc[rt][0], 0, 0, 0);
            acc[rt][1] = __builtin_amdgcn_mfma_f32_16x16x32_f16(af[rt], bf1, acc[rt][1], 0, 0, 0);
            acc[rt][2] = __builtin_amdgcn_mfma_f32_16x16x32_f16(af[rt], bf2, acc[rt][2], 0, 0, 0);
            acc[rt][3] = __builtin_amdgcn_mfma_f32_16x16x32_f16(af[rt], bf3, acc[rt][3], 0, 0, 0);
        }
    }

    // epilogue: tanh + W2 dot -> per-row exp(score) in scL
    float w2v[4], b1v[4];
    #pragma unroll
    for (int ctl = 0; ctl < 4; ++ctl) {
        const int col = wave * 64 + ctl * 16 + (lane & 15);
        w2v[ctl] = W2[col];
        b1v[ctl] = b1[col];
    }

    float sc[4][4];
    #pragma unroll
    for (int rt = 0; rt < 4; ++rt) {
        #pragma unroll
        for (int reg = 0; reg < 4; ++reg) {
            float s = 0.f;
            #pragma unroll
            for (int ctl = 0; ctl < 4; ++ctl) {
                const float x = acc[rt][ctl][reg] + b1v[ctl];
                const float t = 1.f - 2.f / (__expf(2.f * x) + 1.f);
                s = fmaf(t, w2v[ctl], s);
            }
            sc[rt][reg] = s;
        }
    }
    #pragma unroll
    for (int off = 1; off < 16; off <<= 1)
        #pragma unroll
        for (int rt = 0; rt < 4; ++rt)
            #pragma unroll
            for (int reg = 0; reg < 4; ++reg)
                sc[rt][reg] += __shfl_xor(sc[rt][reg], off);

    if ((lane & 15) == 0) {
        #pragma unroll
        for (int rt = 0; rt < 4; ++rt)
            #pragma unroll
            for (int reg = 0; reg < 4; ++reg)
                sp[wave][rt * 16 + (lane >> 4) * 4 + reg] = sc[rt][reg];
    }
    __syncthreads();
    if (tid < 64)
        scL[tid] = __expf(sp[0][tid] + sp[1][tid] + sp[2][tid] + sp[3][tid] + b2[0]);
    __syncthreads();

    // ---- 3. per-gap aggregation, X from LDS (f16), atomics to pacc/pz ----
    // gap(node) = largest g with offL[g] <= node, or -1 if node < offL[0]
    int g_lo, g_hi;
    {
        int node = t0;
        if (node < offL[0]) g_lo = -1;
        else {
            int lo = 0, hi = BATCH - 1;
            while (lo < hi) { int mid = (lo + hi + 1) >> 1; if (offL[mid] <= node) lo = mid; else hi = mid - 1; }
            g_lo = lo;
        }
        node = t0 + 63;
        if (node < offL[0]) g_hi = -1;
        else {
            int lo = 0, hi = BATCH - 1;
            while (lo < hi) { int mid = (lo + hi + 1) >> 1; if (offL[mid] <= node) lo = mid; else hi = mid - 1; }
            g_hi = lo;
        }
    }

    for (int g = (g_lo < 0 ? 0 : g_lo); g <= g_hi; ++g) {
        const int rs = max(t0, offL[g]);
        const int re = min(t0 + 64, (g == BATCH - 1) ? N_NODES : offL[g + 1]);

        float4 a4 = {0.f, 0.f, 0.f, 0.f};
        float z = 0.f;
        for (int i = rs + wave; i < re; i += 4) {
            const int r = i - t0;
            const float p = scL[r];
            // lane l holds cols [4l, 4l+4): chunk col8 = l>>1, half = l&1
            const int byte = r * 512 + ((((lane >> 1) ^ (r & 7))) << 4) + (lane & 1) * 8;
            half4 xv = *reinterpret_cast<const half4*>(
                reinterpret_cast<const char*>(Xs) + byte);
            a4.x = fmaf(p, (float)xv[0], a4.x);
            a4.y = fmaf(p, (float)xv[1], a4.y);
            a4.z = fmaf(p, (float)xv[2], a4.z);
            a4.w = fmaf(p, (float)xv[3], a4.w);
            z += p;
        }
        reinterpret_cast<float4*>(&accL[wave][0])[lane] = a4;
        if (lane == 0) zLs[wave] = z;
        __syncthreads();
        const float v = accL[0][tid] + accL[1][tid] + accL[2][tid] + accL[3][tid];
        atomicAdd(&pacc[g * H + tid], v);
        if (tid == 0) atomicAdd(&pz[g], zLs[0] + zLs[1] + zLs[2] + zLs[3]);
        __syncthreads();   // accL reused by next gap
    }
}

// ---------------------------------------------------------------------------
// Reduce: segment b = union of gaps [max(b-1,0), min(b+1,127)].
// out = sum(acc_g) / sum(z_g). 128 blocks x 256 threads.
// ---------------------------------------------------------------------------
__global__ __launch_bounds__(256) void reduce_kernel(
    const float* __restrict__ pacc, const float* __restrict__ pz,
    float* __restrict__ out)
{
    const int b = blockIdx.x;
    const int tid = threadIdx.x;
    const int g0 = (b == 0) ? 0 : b - 1;
    const int g1 = (b >= BATCH - 1) ? BATCH - 1 : b + 1;

    float r = 0.f, z = 0.f;
    for (int g = g0; g <= g1; ++g) {
        r += pacc[g * H + tid];
        z += pz[g];
    }
    out[b * H + tid] = r / z;
}

// ---------------------------------------------------------------------------
extern "C" void kernel_launch(void* const* d_in, const int* in_sizes, int n_in,
                              void* d_out, int out_size, void* d_ws, size_t ws_size,
                              hipStream_t stream)
{
    const float* X     = (const float*)d_in[0];
    const int* offs    = (const int*)d_in[1];   // int64 in ref -> int32 on device
    const float* W1    = (const float*)d_in[2];
    const float* b1    = (const float*)d_in[3];
    const float* W2    = (const float*)d_in[4];
    const float* b2    = (const float*)d_in[5];
    float* out         = (float*)d_out;

    // workspace layout (floats):
    //   [0, 32768)        pacc   (128 gaps x 256)
    //   [32768, 32896)    pz     (128)
    //   [32896, ...)      W1p    (65536 f16 = 128 KB)
    float* pacc   = (float*)d_ws;
    float* pz     = pacc + BATCH * H;
    _Float16* W1p = (_Float16*)(pz + BATCH);

    prep_kernel<<<160, 256, 0, stream>>>(W1, W1p, pacc, pz);
    fused_kernel<<<NTILES, 256, 0, stream>>>(X, W1p, b1, W2, b2, offs, pacc, pz);
    reduce_kernel<<<BATCH, 256, 0, stream>>>(pacc, pz, out);
}